// Round 4
// baseline (49.447 us; speedup 1.0000x reference)
//
#include <hip/hip_runtime.h>

// E[b] = sum_n h_n^T (0.5*I + 0.1*W) h_n  — single-kernel streaming reduction.
// B=64, N=65536, I=8. h: (B,N,I) f32, W: (8,8) f32.
// Symmetric fold: e = sum_i h_i * (c_i*h_i + sum_{j>i} s_ij*h_j).
// One atomicAdd per block into out[b]; d_out zeroed via async memset node.

#define B_ 64
#define N_ 65536
#define I_ 8
#define BPB 64                        // blocks per batch
#define THREADS 256
#define NPB (N_ / BPB)                // 1024 nodes per block
#define NPT (NPB / THREADS)           // 4 nodes per thread

typedef float floatx4 __attribute__((ext_vector_type(4)));  // native vec for nt-load

__device__ __forceinline__ float uniform_f(float x) {
  return __int_as_float(__builtin_amdgcn_readfirstlane(__float_as_int(x)));
}

__global__ __launch_bounds__(THREADS) void energy_kernel(
    const float* __restrict__ h, const float* __restrict__ W,
    float* __restrict__ out) {
  const int blk = blockIdx.x;
  const int b = blk >> 6;             // blk / BPB
  const int chunk = blk & (BPB - 1);  // blk % BPB
  const int t = threadIdx.x;

  // 36 wave-uniform coefficients, forced into SGPRs.
  float c[I_];
  float s[I_][I_];
#pragma unroll
  for (int i = 0; i < I_; ++i) {
    c[i] = uniform_f(0.5f + 0.1f * W[i * I_ + i]);
#pragma unroll
    for (int j = i + 1; j < I_; ++j)
      s[i][j] = uniform_f(0.1f * (W[i * I_ + j] + W[j * I_ + i]));
  }

  const size_t base = (size_t)b * N_ + (size_t)chunk * NPB;
  float acc = 0.0f;

#pragma unroll
  for (int k = 0; k < NPT; ++k) {
    const size_t node = base + (size_t)k * THREADS + (size_t)t;
    const floatx4* p = reinterpret_cast<const floatx4*>(h + node * I_);
    floatx4 a = __builtin_nontemporal_load(p);      // read-once stream: nt
    floatx4 d = __builtin_nontemporal_load(p + 1);
    float hv[I_] = {a.x, a.y, a.z, a.w, d.x, d.y, d.z, d.w};
    float e = 0.0f;
#pragma unroll
    for (int i = 0; i < I_; ++i) {
      float ti = c[i] * hv[i];
#pragma unroll
      for (int j = i + 1; j < I_; ++j) ti = fmaf(s[i][j], hv[j], ti);
      e = fmaf(hv[i], ti, e);
    }
    acc += e;
  }

  // Wave(64)-wide shuffle reduction, then cross-wave via LDS.
#pragma unroll
  for (int off = 32; off > 0; off >>= 1)
    acc += __shfl_down(acc, off, 64);

  __shared__ float wsum[THREADS / 64];
  const int wave = t >> 6;
  const int lane = t & 63;
  if (lane == 0) wsum[wave] = acc;
  __syncthreads();
  if (t == 0) {
    float sum = 0.0f;
#pragma unroll
    for (int w = 0; w < THREADS / 64; ++w) sum += wsum[w];
    atomicAdd(&out[b], sum);          // 64 adds per address, device scope
  }
}

extern "C" void kernel_launch(void* const* d_in, const int* in_sizes, int n_in,
                              void* d_out, int out_size, void* d_ws, size_t ws_size,
                              hipStream_t stream) {
  const float* h = (const float*)d_in[0];
  const float* W = (const float*)d_in[1];
  float* out = (float*)d_out;

  (void)hipMemsetAsync(out, 0, B_ * sizeof(float), stream);  // graph memset node
  energy_kernel<<<B_ * BPB, THREADS, 0, stream>>>(h, W, out);
}

// Round 5
// 26.581 us; speedup vs baseline: 1.8602x; 1.8602x over previous
//
#include <hip/hip_runtime.h>

// E[b] = sum_n h_n^T (0.5*I + 0.1*W) h_n  — pure streaming reduction.
// B=64, N=65536, I=8. h: (B,N,I) f32, W: (8,8) f32.
// Symmetric fold: e = sum_i h_i * (c_i*h_i + sum_{j>i} s_ij*h_j),
//   c_i = 0.5 + 0.1*W_ii, s_ij = 0.1*(W_ij + W_ji).
// Two-kernel deterministic reduction. Plain (cached) loads — nt loads
// measured 2x slower on this pattern (round 4: 49.4us vs 26.2us).

#define B_ 64
#define N_ 65536
#define I_ 8
#define BPB 32                        // blocks per batch
#define THREADS 256
#define NPB (N_ / BPB)                // 2048 nodes per block
#define NPT (NPB / THREADS)           // 8 nodes per thread

__device__ __forceinline__ float uniform_f(float x) {
  return __int_as_float(__builtin_amdgcn_readfirstlane(__float_as_int(x)));
}

__global__ __launch_bounds__(THREADS) void energy_partial_kernel(
    const float* __restrict__ h, const float* __restrict__ W,
    float* __restrict__ partial) {
  const int blk = blockIdx.x;
  const int b = blk >> 5;             // blk / BPB
  const int chunk = blk & (BPB - 1);  // blk % BPB
  const int t = threadIdx.x;

  // 36 wave-uniform coefficients, forced into SGPRs.
  float c[I_];
  float s[I_][I_];
#pragma unroll
  for (int i = 0; i < I_; ++i) {
    c[i] = uniform_f(0.5f + 0.1f * W[i * I_ + i]);
#pragma unroll
    for (int j = i + 1; j < I_; ++j)
      s[i][j] = uniform_f(0.1f * (W[i * I_ + j] + W[j * I_ + i]));
  }

  const size_t base = (size_t)b * N_ + (size_t)chunk * NPB;
  float acc = 0.0f;

#pragma unroll
  for (int k = 0; k < NPT; ++k) {
    const size_t node = base + (size_t)k * THREADS + (size_t)t;
    const float4* p = reinterpret_cast<const float4*>(h + node * I_);
    float4 a = p[0];
    float4 d = p[1];
    float hv[I_] = {a.x, a.y, a.z, a.w, d.x, d.y, d.z, d.w};
    float e = 0.0f;
#pragma unroll
    for (int i = 0; i < I_; ++i) {
      float ti = c[i] * hv[i];
#pragma unroll
      for (int j = i + 1; j < I_; ++j) ti = fmaf(s[i][j], hv[j], ti);
      e = fmaf(hv[i], ti, e);
    }
    acc += e;
  }

  // Wave(64)-wide shuffle reduction, then cross-wave via LDS.
#pragma unroll
  for (int off = 32; off > 0; off >>= 1)
    acc += __shfl_down(acc, off, 64);

  __shared__ float wsum[THREADS / 64];
  const int wave = t >> 6;
  const int lane = t & 63;
  if (lane == 0) wsum[wave] = acc;
  __syncthreads();
  if (t == 0) {
    float sum = 0.0f;
#pragma unroll
    for (int w = 0; w < THREADS / 64; ++w) sum += wsum[w];
    partial[blk] = sum;
  }
}

__global__ void energy_final_kernel(const float* __restrict__ partial,
                                    float* __restrict__ out) {
  const int b = threadIdx.x;
  if (b < B_) {
    const float4* p = reinterpret_cast<const float4*>(partial + (size_t)b * BPB);
    float sum = 0.0f;
#pragma unroll
    for (int q = 0; q < BPB / 4; ++q) {    // 8 independent float4 loads
      float4 v = p[q];
      sum += (v.x + v.y) + (v.z + v.w);
    }
    out[b] = sum;
  }
}

extern "C" void kernel_launch(void* const* d_in, const int* in_sizes, int n_in,
                              void* d_out, int out_size, void* d_ws, size_t ws_size,
                              hipStream_t stream) {
  const float* h = (const float*)d_in[0];
  const float* W = (const float*)d_in[1];
  float* partial = (float*)d_ws;      // B_*BPB = 2048 floats
  float* out = (float*)d_out;

  energy_partial_kernel<<<B_ * BPB, THREADS, 0, stream>>>(h, W, partial);
  energy_final_kernel<<<1, 64, 0, stream>>>(partial, out);
}